// Round 9
// baseline (5057.200 us; speedup 1.0000x reference)
//
#include <hip/hip_runtime.h>
#include <math.h>

// POSTagEncoder: expert-routed linear -> 1-layer LSTM (i,f,g,o) -> time max-pool.
// S=8192, D=128, E=48. Output [1,128] fp32.
//
// Round-18: 8-WAVE RETRY with the vmcnt hazard class removed.
// R8's reorder regressed (4161->4321) -> R6 ordering restored conceptually.
// R7 (8 waves, manual asm xg loads) failed 0.109 absmax; line-by-line audit
// found no mapping error -- the un-verifiable feature was the manual vmcnt(7)
// invariant (any compiler-emitted vmcnt-counted op corrupts it). This retry
// keeps R7's verified mapping but loads xg via PLAIN C LOADS: the compiler
// does its own (always-correct) vmcnt accounting, and the asm barrier's
// "memory" clobber pins each load inside its issuing step -> 8-deep prefetch
// preserved without manual counters.
// Structure: 8 waves (2/SIMD), 16 dims/wave, 4 gates x 4 K-chunks = 16 MFMAs
// per wave per step (per-SIMD pipe time unchanged at 32 MFMAs = ~512 cyc);
// sibling wave fills the ~477-cyc phase-aligned stall of the 4-wave version.
// All 16 MFMA B-columns identical -> lane's gate value = reg c&3 (sel4).
// Mirrors (4 lanes/dim) write scratch rows 128..511. lgkm-only barrier.

#define SEQ   8192
#define DIM   128
#define NGATE 512
#define NEXP  48

typedef _Float16 v8h  __attribute__((ext_vector_type(8)));
typedef float    v4f  __attribute__((ext_vector_type(4)));

__device__ __forceinline__ float sigm_fast(float x) {
    return __fdividef(1.0f, 1.0f + __expf(-x));   // inf-safe both ends
}
__device__ __forceinline__ float tanh_fast(float x) {
    float e = __expf(2.0f * x);
    return 1.0f - __fdividef(2.0f, e + 1.0f);     // +-1 at saturation
}
__device__ __forceinline__ v8h pack8(float4 a, float4 b) {   // RNE converts
    v8h r;
    r[0]=(_Float16)a.x; r[1]=(_Float16)a.y; r[2]=(_Float16)a.z; r[3]=(_Float16)a.w;
    r[4]=(_Float16)b.x; r[5]=(_Float16)b.y; r[6]=(_Float16)b.z; r[7]=(_Float16)b.w;
    return r;
}
// pick reg (c&3) of a v4f C-fragment (all 16 MFMA columns identical here)
__device__ __forceinline__ float sel4(v4f V, int c) {
    float v01 = (c & 1) ? V[1] : V[0];
    float v23 = (c & 1) ? V[3] : V[2];
    return (c & 2) ? v23 : v01;
}

// ---------------------------------------------------------------------------
// K1a: z[s] = W_exp[pos_ids[s]] @ embs[s] + b_exp  -> xg[s*512 + 0..128)
// ---------------------------------------------------------------------------
__global__ __launch_bounds__(64) void expert_gemv(
    const float* __restrict__ embs, const int* __restrict__ pos_ids,
    const float* __restrict__ W_exp, const float* __restrict__ b_exp,
    float* __restrict__ xg)
{
    __shared__ float Wl[DIM * DIM];          // 64KB, rows XOR-swizzled
    const int e     = blockIdx.x % NEXP;
    const int slice = blockIdx.x / NEXP;     // 0..7
    const int tid   = threadIdx.x;           // 0..63

    const float4* Wg = (const float4*)(W_exp + (size_t)e * DIM * DIM);
    #pragma unroll 4
    for (int it = 0; it < 64; ++it) {
        int idx = it * 64 + tid;             // 0..4095 float4s
        int r = idx >> 5, c4 = idx & 31;
        float4 v = Wg[idx];
        *(float4*)&Wl[r * DIM + (((c4 ^ (r & 31))) << 2)] = v;
    }
    const float b0 = b_exp[e * DIM + tid];
    const float b1 = b_exp[e * DIM + 64 + tid];
    __syncthreads();

    const int r0 = tid, r1 = tid + 64;
    const int sw0 = r0 & 31, sw1 = r1 & 31;
    const int sBeg = slice * 1024, sEnd = sBeg + 1024;
    for (int base = sBeg; base < sEnd; base += 64) {
        int pid = pos_ids[base + tid];
        unsigned long long m = __ballot(pid == e);
        while (m) {
            int t = __builtin_ctzll(m);
            m &= m - 1;
            int s = base + t;
            const float4* ev = (const float4*)(embs + (size_t)s * DIM);
            float a0 = b0, a1 = b1;
            #pragma unroll
            for (int j4 = 0; j4 < 32; ++j4) {
                float4 x  = ev[j4];
                float4 w0 = *(const float4*)&Wl[r0 * DIM + ((j4 ^ sw0) << 2)];
                float4 w1 = *(const float4*)&Wl[r1 * DIM + ((j4 ^ sw1) << 2)];
                a0 = fmaf(w0.x,x.x,fmaf(w0.y,x.y,fmaf(w0.z,x.z,fmaf(w0.w,x.w,a0))));
                a1 = fmaf(w1.x,x.x,fmaf(w1.y,x.y,fmaf(w1.z,x.z,fmaf(w1.w,x.w,a1))));
            }
            float* zp = xg + (size_t)s * NGATE;
            zp[tid]      = a0;
            zp[tid + 64] = a1;
        }
    }
}

// ---------------------------------------------------------------------------
// K1b: gates = W_ih @ z + b_ih + b_hh, stored PERMUTED: xg[s][dim*4 + gate]
// ---------------------------------------------------------------------------
__global__ __launch_bounds__(256) void gate_gemm(
    const float* __restrict__ W_ih, const float* __restrict__ b_ih,
    const float* __restrict__ b_hh, float* __restrict__ xg)
{
    __shared__ float zl[32 * DIM];    // 16KB
    __shared__ float Wl[64 * DIM];    // 32KB
    const int tid = threadIdx.x;
    const int s0  = blockIdx.x * 32;

    #pragma unroll
    for (int it = 0; it < 4; ++it) {
        int idx = it * 256 + tid;
        int tok = idx >> 5, c4 = idx & 31;
        float4 v = *(const float4*)(xg + ((size_t)(s0 + tok)) * NGATE + (c4 << 2));
        *(float4*)&zl[tok * DIM + (((c4 ^ (tok & 31))) << 2)] = v;
    }
    __syncthreads();

    const int lane = tid & 63;
    const int tg   = tid >> 6;
    const int swr  = lane & 31;

    for (int ch = 0; ch < 8; ++ch) {
        #pragma unroll
        for (int it = 0; it < 8; ++it) {
            int idx = it * 256 + tid;
            int r = idx >> 5, c4 = idx & 31;
            float4 v = *(const float4*)(W_ih + ((size_t)(ch * 64 + r)) * DIM + (c4 << 2));
            *(float4*)&Wl[r * DIM + ((c4 ^ (r & 31)) << 2)] = v;
        }
        __syncthreads();

        const int row = ch * 64 + lane;      // 0..511
        const float bias = b_ih[row] + b_hh[row];
        float acc[8];
        #pragma unroll
        for (int k = 0; k < 8; ++k) acc[k] = bias;
        #pragma unroll 8
        for (int j4 = 0; j4 < 32; ++j4) {
            float4 w = *(const float4*)&Wl[lane * DIM + ((j4 ^ swr) << 2)];
            #pragma unroll
            for (int k = 0; k < 8; ++k) {
                int tok = tg * 8 + k;
                float4 z = *(const float4*)&zl[tok * DIM + ((j4 ^ (tok & 31)) << 2)];
                acc[k] = fmaf(w.x,z.x,fmaf(w.y,z.y,fmaf(w.z,z.z,fmaf(w.w,z.w,acc[k]))));
            }
        }
        const int pidx = ((row & 127) << 2) + (row >> 7);   // dim*4 + gate
        #pragma unroll
        for (int k = 0; k < 8; ++k) {
            int tok = tg * 8 + k;
            xg[((size_t)(s0 + tok)) * NGATE + pidx] = acc[k];
        }
        __syncthreads();
    }
}

// ---------------------------------------------------------------------------
// K2: MFMA LSTM scan + max-pool. ONE block, 512 threads (8 waves, 2/SIMD).
// ---------------------------------------------------------------------------
__global__ __launch_bounds__(512, 2) void lstm_scan(
    const float* __restrict__ xg, const float* __restrict__ W_hh,
    float* __restrict__ out)
{
    const int T    = threadIdx.x;
    const int w8   = T >> 6;         // wave id 0..7: owns dims [16*w8, 16*w8+16)
    const int lane = T & 63;
    const int q    = lane >> 4;      // quad 0..3 (k-group)
    const int c    = lane & 15;      // A row-in-tile; C column
    const int q8   = q * 8;
    const int m    = c >> 2;         // mirror 0..3 (4 lanes per dim)
    const int d    = w8 * 16 + q * 4 + (c & 3);
    const int dw   = d + 128 * m;    // m=0 canonical; m>0 scratch rows

    __shared__ __align__(16) _Float16 hbuf[2][512];

    // ---- A-fragments: gate G tile rows = G*128 + w8*16 + c, 4 K-chunks ----
#define LOADA(G) \
    v8h a##G##_0, a##G##_1, a##G##_2, a##G##_3; { \
        const float4* p = (const float4*)(W_hh + \
            (size_t)((G) * 128 + w8 * 16 + c) * DIM) + q * 2; \
        a##G##_0 = pack8(p[ 0], p[ 1]); \
        a##G##_1 = pack8(p[ 8], p[ 9]); \
        a##G##_2 = pack8(p[16], p[17]); \
        a##G##_3 = pack8(p[24], p[25]); }
    LOADA(0) LOADA(1) LOADA(2) LOADA(3)
#undef LOADA

    float cst  = 0.0f;
    float hmax = -INFINITY;

    if (T < DIM) hbuf[0][T] = (_Float16)0.0f;   // h_0 = 0 (canonical rows)
    __syncthreads();

    // per-lane xg column pointer ([t][dim][gate] layout)
    const float* xp = xg + 4 * d;

    // 8 prefetched xg rows, COMPILER-TRACKED loads (compiler inserts its own
    // vmcnt waits before each use; the asm barrier's "memory" clobber pins
    // every load inside its issuing step -> 8-deep prefetch preserved).
    v4f X0, X1, X2, X3, X4, X5, X6, X7;
#define PRELD(n) X##n = *(const v4f*)(xp + (size_t)(n) * NGATE);
    PRELD(0) PRELD(1) PRELD(2) PRELD(3) PRELD(4) PRELD(5) PRELD(6) PRELD(7)
#undef PRELD

    const v4f Z4 = {0.0f, 0.0f, 0.0f, 0.0f};

#define MF(G,K,B,CIN) __builtin_amdgcn_mfma_f32_16x16x32_f16(a##G##_##K, B, CIN, 0, 0, 0)

#define STEP(XV, tn, bf, nbf) { \
    const v8h B0 = *(const v8h*)&hbuf[bf][ 0 + q8]; \
    const v8h B1 = *(const v8h*)&hbuf[bf][32 + q8]; \
    const v8h B2 = *(const v8h*)&hbuf[bf][64 + q8]; \
    const v8h B3 = *(const v8h*)&hbuf[bf][96 + q8]; \
    /* chunk-major, 4 independent chains (dep spacing 4) */ \
    v4f ci = MF(0,0,B0,Z4);  v4f cf = MF(1,0,B0,Z4); \
    v4f cg = MF(2,0,B0,Z4);  v4f co = MF(3,0,B0,Z4); \
    /* xg consume + next prefetch (compiler-tracked) */ \
    const v4f xcur = XV; \
    XV = *(const v4f*)(xp + (size_t)(tn) * NGATE); \
    ci = MF(0,1,B1,ci);  cf = MF(1,1,B1,cf); \
    cg = MF(2,1,B1,cg);  co = MF(3,1,B1,co); \
    ci = MF(0,2,B2,ci);  cf = MF(1,2,B2,cf); \
    cg = MF(2,2,B2,cg);  co = MF(3,2,B2,co); \
    ci = MF(0,3,B3,ci);  cf = MF(1,3,B3,cf); \
    cg = MF(2,3,B3,cg);  co = MF(3,3,B3,co); \
    /* epilogue on ALL lanes (4-fold mirror); sibling wave fills gaps */ \
    const float pi = sel4(ci, c) + xcur[0]; \
    const float pf = sel4(cf, c) + xcur[1]; \
    const float pg = sel4(cg, c) + xcur[2]; \
    const float po = sel4(co, c) + xcur[3]; \
    const float iv = sigm_fast(pi); \
    const float fv = sigm_fast(pf); \
    const float gv = tanh_fast(pg); \
    const float ov = sigm_fast(po); \
    cst = fmaf(fv, cst, iv * gv); \
    const float h = ov * tanh_fast(cst); \
    hmax = fmaxf(hmax, h); \
    hbuf[nbf][dw] = (_Float16)h; \
    asm volatile("s_waitcnt lgkmcnt(0)\n\ts_barrier" ::: "memory"); }

    for (int t = 0; t < SEQ; t += 8) {
        const int tn0 = (t +  8 < SEQ) ? t +  8 : SEQ - 1;
        const int tn1 = (t +  9 < SEQ) ? t +  9 : SEQ - 1;
        const int tn2 = (t + 10 < SEQ) ? t + 10 : SEQ - 1;
        const int tn3 = (t + 11 < SEQ) ? t + 11 : SEQ - 1;
        const int tn4 = (t + 12 < SEQ) ? t + 12 : SEQ - 1;
        const int tn5 = (t + 13 < SEQ) ? t + 13 : SEQ - 1;
        const int tn6 = (t + 14 < SEQ) ? t + 14 : SEQ - 1;
        const int tn7 = (t + 15 < SEQ) ? t + 15 : SEQ - 1;
        STEP(X0, tn0, 0, 1)
        STEP(X1, tn1, 1, 0)
        STEP(X2, tn2, 0, 1)
        STEP(X3, tn3, 1, 0)
        STEP(X4, tn4, 0, 1)
        STEP(X5, tn5, 1, 0)
        STEP(X6, tn6, 0, 1)
        STEP(X7, tn7, 1, 0)
    }
#undef STEP
#undef MF

    if (c < 4) out[d] = hmax;   // 16 unique dims per wave -> out[1][128]
}

// ---------------------------------------------------------------------------
extern "C" void kernel_launch(void* const* d_in, const int* in_sizes, int n_in,
                              void* d_out, int out_size, void* d_ws, size_t ws_size,
                              hipStream_t stream)
{
    const float* embs  = (const float*)d_in[0];
    const int*   pos   = (const int*)  d_in[1];
    const float* W_exp = (const float*)d_in[2];
    const float* b_exp = (const float*)d_in[3];
    const float* W_ih  = (const float*)d_in[4];
    const float* W_hh  = (const float*)d_in[5];
    const float* b_ih  = (const float*)d_in[6];
    const float* b_hh  = (const float*)d_in[7];
    float* out = (float*)d_out;
    float* xg  = (float*)d_ws;   // [SEQ][512] fp32 = 16 MB

    expert_gemv<<<dim3(NEXP * 8), 64, 0, stream>>>(embs, pos, W_exp, b_exp, xg);
    gate_gemm  <<<dim3(256), 256, 0, stream>>>(W_ih, b_ih, b_hh, xg);
    lstm_scan  <<<dim3(1), 512, 0, stream>>>(xg, W_hh, out);
}

// Round 10
// 4331.701 us; speedup vs baseline: 1.1675x; 1.1675x over previous
//
#include <hip/hip_runtime.h>
#include <math.h>

// POSTagEncoder: expert-routed linear -> 1-layer LSTM (i,f,g,o) -> time max-pool.
// S=8192, D=128, E=48. Output [1,128] fp32.
//
// Round-19: EXACT REVERT to the session-best verified kernel (R6 = round-15
// form, measured 4339.0us total / 4161us scan, absmax 0.00390625).
// Post-R6 structural attempts all failed or regressed:
//   R7  8-wave (manual vmcnt):  absmax 0.109 (vmcnt invariant hazard)
//   R8  chunk-0 front-load:     4321 scan (epilogue-interleave delay)
//   R9  8-wave (tracked loads): 4851 scan (lockstep contention: 6x bank
//       conflicts, bigger barrier, no cross-wave fill; MfmaUtil DROPPED)
// Refined model: 32 MFMAs/wave at measured ~19.4cyc/SIMD pipe cadence (m06
// ceiling) = ~620 cyc + ~110 serial tail + ~100-150 barrier/drain + ~60
// front = ~950-1050 floor vs 1219 measured -- within ~15-20%, with the
// all-to-all h broadcast per step being what MFMA fundamentally buys.
//
// Kernel structure (verified): 4 waves 1/SIMD; K-chunk slot rotation
// (slot 0 = own h-slice, pre-barrier read); gate-phase split (i,f MFMAs ->
// g,o MFMAs with i,f epilogue interleaved); xg packet in chunk-0 stall
// window; lgkmcnt(1) barrier; branch-free epilogue (mirror lanes write
// scratch rows 128..255); [t][dim][gate] xg layout; 8 asm xg loads in
// flight with manual vmcnt(7).

#define SEQ   8192
#define DIM   128
#define NGATE 512
#define NEXP  48

typedef _Float16 v8h  __attribute__((ext_vector_type(8)));
typedef float    v4f  __attribute__((ext_vector_type(4)));

__device__ __forceinline__ float sigm_fast(float x) {
    return __fdividef(1.0f, 1.0f + __expf(-x));   // inf-safe both ends
}
__device__ __forceinline__ float tanh_fast(float x) {
    float e = __expf(2.0f * x);
    return 1.0f - __fdividef(2.0f, e + 1.0f);     // +-1 at saturation
}
__device__ __forceinline__ v8h pack8(float4 a, float4 b) {   // RNE converts
    v8h r;
    r[0]=(_Float16)a.x; r[1]=(_Float16)a.y; r[2]=(_Float16)a.z; r[3]=(_Float16)a.w;
    r[4]=(_Float16)b.x; r[5]=(_Float16)b.y; r[6]=(_Float16)b.z; r[7]=(_Float16)b.w;
    return r;
}
// select component (c&1,c&2) from A (half 0) or B (half 1) per (c&4)
__device__ __forceinline__ float selv(v4f A, v4f B, int c) {
    float a01 = (c & 1) ? A[1] : A[0];
    float a23 = (c & 1) ? A[3] : A[2];
    float av  = (c & 2) ? a23 : a01;
    float b01 = (c & 1) ? B[1] : B[0];
    float b23 = (c & 1) ? B[3] : B[2];
    float bv  = (c & 2) ? b23 : b01;
    return (c & 4) ? bv : av;
}

// ---------------------------------------------------------------------------
// K1a: z[s] = W_exp[pos_ids[s]] @ embs[s] + b_exp  -> xg[s*512 + 0..128)
// ---------------------------------------------------------------------------
__global__ __launch_bounds__(64) void expert_gemv(
    const float* __restrict__ embs, const int* __restrict__ pos_ids,
    const float* __restrict__ W_exp, const float* __restrict__ b_exp,
    float* __restrict__ xg)
{
    __shared__ float Wl[DIM * DIM];          // 64KB, rows XOR-swizzled
    const int e     = blockIdx.x % NEXP;
    const int slice = blockIdx.x / NEXP;     // 0..7
    const int tid   = threadIdx.x;           // 0..63

    const float4* Wg = (const float4*)(W_exp + (size_t)e * DIM * DIM);
    #pragma unroll 4
    for (int it = 0; it < 64; ++it) {
        int idx = it * 64 + tid;             // 0..4095 float4s
        int r = idx >> 5, c4 = idx & 31;
        float4 v = Wg[idx];
        *(float4*)&Wl[r * DIM + (((c4 ^ (r & 31))) << 2)] = v;
    }
    const float b0 = b_exp[e * DIM + tid];
    const float b1 = b_exp[e * DIM + 64 + tid];
    __syncthreads();

    const int r0 = tid, r1 = tid + 64;
    const int sw0 = r0 & 31, sw1 = r1 & 31;
    const int sBeg = slice * 1024, sEnd = sBeg + 1024;
    for (int base = sBeg; base < sEnd; base += 64) {
        int pid = pos_ids[base + tid];
        unsigned long long m = __ballot(pid == e);
        while (m) {
            int t = __builtin_ctzll(m);
            m &= m - 1;
            int s = base + t;
            const float4* ev = (const float4*)(embs + (size_t)s * DIM);
            float a0 = b0, a1 = b1;
            #pragma unroll
            for (int j4 = 0; j4 < 32; ++j4) {
                float4 x  = ev[j4];
                float4 w0 = *(const float4*)&Wl[r0 * DIM + ((j4 ^ sw0) << 2)];
                float4 w1 = *(const float4*)&Wl[r1 * DIM + ((j4 ^ sw1) << 2)];
                a0 = fmaf(w0.x,x.x,fmaf(w0.y,x.y,fmaf(w0.z,x.z,fmaf(w0.w,x.w,a0))));
                a1 = fmaf(w1.x,x.x,fmaf(w1.y,x.y,fmaf(w1.z,x.z,fmaf(w1.w,x.w,a1))));
            }
            float* zp = xg + (size_t)s * NGATE;
            zp[tid]      = a0;
            zp[tid + 64] = a1;
        }
    }
}

// ---------------------------------------------------------------------------
// K1b: gates = W_ih @ z + b_ih + b_hh, stored PERMUTED: xg[s][dim*4 + gate]
// ---------------------------------------------------------------------------
__global__ __launch_bounds__(256) void gate_gemm(
    const float* __restrict__ W_ih, const float* __restrict__ b_ih,
    const float* __restrict__ b_hh, float* __restrict__ xg)
{
    __shared__ float zl[32 * DIM];    // 16KB
    __shared__ float Wl[64 * DIM];    // 32KB
    const int tid = threadIdx.x;
    const int s0  = blockIdx.x * 32;

    #pragma unroll
    for (int it = 0; it < 4; ++it) {
        int idx = it * 256 + tid;
        int tok = idx >> 5, c4 = idx & 31;
        float4 v = *(const float4*)(xg + ((size_t)(s0 + tok)) * NGATE + (c4 << 2));
        *(float4*)&zl[tok * DIM + (((c4 ^ (tok & 31))) << 2)] = v;
    }
    __syncthreads();

    const int lane = tid & 63;
    const int tg   = tid >> 6;
    const int swr  = lane & 31;

    for (int ch = 0; ch < 8; ++ch) {
        #pragma unroll
        for (int it = 0; it < 8; ++it) {
            int idx = it * 256 + tid;
            int r = idx >> 5, c4 = idx & 31;
            float4 v = *(const float4*)(W_ih + ((size_t)(ch * 64 + r)) * DIM + (c4 << 2));
            *(float4*)&Wl[r * DIM + ((c4 ^ (r & 31)) << 2)] = v;
        }
        __syncthreads();

        const int row = ch * 64 + lane;      // 0..511
        const float bias = b_ih[row] + b_hh[row];
        float acc[8];
        #pragma unroll
        for (int k = 0; k < 8; ++k) acc[k] = bias;
        #pragma unroll 8
        for (int j4 = 0; j4 < 32; ++j4) {
            float4 w = *(const float4*)&Wl[lane * DIM + ((j4 ^ swr) << 2)];
            #pragma unroll
            for (int k = 0; k < 8; ++k) {
                int tok = tg * 8 + k;
                float4 z = *(const float4*)&zl[tok * DIM + ((j4 ^ (tok & 31)) << 2)];
                acc[k] = fmaf(w.x,z.x,fmaf(w.y,z.y,fmaf(w.z,z.z,fmaf(w.w,z.w,acc[k]))));
            }
        }
        const int pidx = ((row & 127) << 2) + (row >> 7);   // dim*4 + gate
        #pragma unroll
        for (int k = 0; k < 8; ++k) {
            int tok = tg * 8 + k;
            xg[((size_t)(s0 + tok)) * NGATE + pidx] = acc[k];
        }
        __syncthreads();
    }
}

// ---------------------------------------------------------------------------
// K2: MFMA LSTM scan + max-pool. ONE block, 256 threads (4 waves, 1/SIMD).
// ---------------------------------------------------------------------------
__global__ __launch_bounds__(256, 1) void lstm_scan(
    const float* __restrict__ xg, const float* __restrict__ W_hh,
    float* __restrict__ out)
{
    const int T    = threadIdx.x;
    const int wg   = T >> 6;         // wave id: owns dims [32*wg, 32*wg+32)
    const int lane = T & 63;
    const int q    = lane >> 4;      // quad 0..3
    const int c    = lane & 15;      // A row-in-tile; C column
    const int q8   = q * 8;
    // lanes c>=8 mirror c-8 (duplicate epilogue; write to scratch rows)
    const int d    = wg * 32 + q * 4 + (c & 3) + ((c & 4) ? 16 : 0);
    const int dw   = d + ((c & 8) ? 128 : 0);   // mirror half -> rows 128..255

    __shared__ __align__(16) _Float16 hbuf[2][256];

    // K-chunk slot rotation: slot k <-> chunk (wg+k)&3; slot 0 == own slice.
    const int j0 = wg & 3, j1 = (wg + 1) & 3, j2 = (wg + 2) & 3, j3 = (wg + 3) & 3;
    const int bo0 = j0 * 32 + q8, bo1 = j1 * 32 + q8,
              bo2 = j2 * 32 + q8, bo3 = j3 * 32 + q8;

    // ---- A-fragments: tile (gate G, half H) rows = G*128 + wg*32 + H*16 + c,
    //      4 K-chunks PRE-ROTATED into slots; MFMA-only use -> AGPR-resident --
#define LOADA(G,H) \
    v8h a##G##H##0, a##G##H##1, a##G##H##2, a##G##H##3; { \
        const float4* p = (const float4*)(W_hh + \
            (size_t)((G) * 128 + wg * 32 + (H) * 16 + c) * DIM) + q * 2; \
        a##G##H##0 = pack8(p[8*j0], p[8*j0+1]); \
        a##G##H##1 = pack8(p[8*j1], p[8*j1+1]); \
        a##G##H##2 = pack8(p[8*j2], p[8*j2+1]); \
        a##G##H##3 = pack8(p[8*j3], p[8*j3+1]); }
    LOADA(0,0) LOADA(0,1) LOADA(1,0) LOADA(1,1)
    LOADA(2,0) LOADA(2,1) LOADA(3,0) LOADA(3,1)
#undef LOADA

    float cst  = 0.0f;
    float hmax = -INFINITY;

    if (T < DIM) hbuf[0][T] = (_Float16)0.0f;   // h_0 = 0 (rows 0..127 only)
    __syncthreads();   // drains vmcnt(0): HW counter = 0 at this point; all
                       // compiler-tracked loads (W_hh) are complete.

    // own-slot B for step 0 (zeros; lgkm-tracked by compiler)
    v8h B0cur = *(const v8h*)&hbuf[0][bo0];

    // per-lane xg column pointer ([t][dim][gate] layout)
    const float* xp = xg + 4 * d;

    // 8 asm loads in flight (rows 0..7). Invariant before step t's wait:
    // outstanding = rows t..t+7; vmcnt(7) completes exactly row t.
    v4f X0, X1, X2, X3, X4, X5, X6, X7;
#define PRELD(n) { const float* _p = xp + (size_t)(n) * NGATE; \
    asm volatile("global_load_dwordx4 %0, %1, off" : "=v"(X##n) : "v"(_p)); }
    PRELD(0) PRELD(1) PRELD(2) PRELD(3) PRELD(4) PRELD(5) PRELD(6) PRELD(7)
#undef PRELD

    const v4f Z4 = {0.0f, 0.0f, 0.0f, 0.0f};

#define MF(G,H,K,B,CIN) __builtin_amdgcn_mfma_f32_16x16x32_f16(a##G##H##K, B, CIN, 0, 0, 0)

#define STEP(XV, tn, bf, nbf) { \
    /* foreign MFMA B slices: issue immediately at barrier release */ \
    const v8h B1 = *(const v8h*)&hbuf[bf][bo1]; \
    const v8h B2 = *(const v8h*)&hbuf[bf][bo2]; \
    const v8h B3 = *(const v8h*)&hbuf[bf][bo3]; \
    /* ---- phase A: gates i,f -- 4 chains, chunk-major ---- */ \
    v4f c00 = MF(0,0,0,B0cur,Z4);  v4f c01 = MF(0,1,0,B0cur,Z4); \
    v4f c10 = MF(1,0,0,B0cur,Z4);  v4f c11 = MF(1,1,0,B0cur,Z4); \
    /* xg packet in the first MFMA stall window (B1 latency cover) */ \
    asm volatile("s_waitcnt vmcnt(7)" : "+v"(XV));  /* row-t load complete */ \
    const v4f xcur = XV; \
    { const float* _p = xp + (size_t)(tn) * NGATE; \
      asm volatile("global_load_dwordx4 %0, %1, off" : "=v"(XV) : "v"(_p)); } \
    c00 = MF(0,0,1,B1,c00);  c01 = MF(0,1,1,B1,c01); \
    c10 = MF(1,0,1,B1,c10);  c11 = MF(1,1,1,B1,c11); \
    c00 = MF(0,0,2,B2,c00);  c01 = MF(0,1,2,B2,c01); \
    c10 = MF(1,0,2,B2,c10);  c11 = MF(1,1,2,B2,c11); \
    c00 = MF(0,0,3,B3,c00);  c01 = MF(0,1,3,B3,c01); \
    c10 = MF(1,0,3,B3,c10);  c11 = MF(1,1,3,B3,c11); \
    /* ---- phase B: gates g,o MFMAs with i,f epilogue interleaved ---- */ \
    v4f c20 = MF(2,0,0,B0cur,Z4);  v4f c21 = MF(2,1,0,B0cur,Z4); \
    v4f c30 = MF(3,0,0,B0cur,Z4);  v4f c31 = MF(3,1,0,B0cur,Z4); \
    c20 = MF(2,0,1,B1,c20);  c21 = MF(2,1,1,B1,c21); \
    c30 = MF(3,0,1,B1,c30);  c31 = MF(3,1,1,B1,c31); \
    const float pi = selv(c00, c01, c) + xcur[0]; \
    const float pf = selv(c10, c11, c) + xcur[1]; \
    c20 = MF(2,0,2,B2,c20);  c21 = MF(2,1,2,B2,c21); \
    c30 = MF(3,0,2,B2,c30);  c31 = MF(3,1,2,B2,c31); \
    const float iv = sigm_fast(pi); \
    const float fv = sigm_fast(pf); \
    c20 = MF(2,0,3,B3,c20);  c21 = MF(2,1,3,B3,c21); \
    c30 = MF(3,0,3,B3,c30);  c31 = MF(3,1,3,B3,c31); \
    /* ---- phase C: g,o epilogue + state update (short tail) ---- */ \
    const float pg = selv(c20, c21, c) + xcur[2]; \
    const float po = selv(c30, c31, c) + xcur[3]; \
    const float gv = tanh_fast(pg); \
    const float ov = sigm_fast(po); \
    cst = fmaf(fv, cst, iv * gv); \
    const float h = ov * tanh_fast(cst); \
    hmax = fmaxf(hmax, h); \
    hbuf[nbf][dw] = (_Float16)h; \
    /* own-slot B for NEXT step: same-wave ds ops are pipe-ordered */ \
    B0cur = *(const v8h*)&hbuf[nbf][bo0]; \
    /* lgkmcnt(1): h ds_write drained (cross-wave visible at barrier); */ \
    /* B0cur's ds_read latency overlaps the barrier wait.              */ \
    asm volatile("s_waitcnt lgkmcnt(1)\n\ts_barrier" ::: "memory"); }

    for (int t = 0; t < SEQ; t += 8) {
        const int tn0 = (t +  8 < SEQ) ? t +  8 : SEQ - 1;
        const int tn1 = (t +  9 < SEQ) ? t +  9 : SEQ - 1;
        const int tn2 = (t + 10 < SEQ) ? t + 10 : SEQ - 1;
        const int tn3 = (t + 11 < SEQ) ? t + 11 : SEQ - 1;
        const int tn4 = (t + 12 < SEQ) ? t + 12 : SEQ - 1;
        const int tn5 = (t + 13 < SEQ) ? t + 13 : SEQ - 1;
        const int tn6 = (t + 14 < SEQ) ? t + 14 : SEQ - 1;
        const int tn7 = (t + 15 < SEQ) ? t + 15 : SEQ - 1;
        STEP(X0, tn0, 0, 1)
        STEP(X1, tn1, 1, 0)
        STEP(X2, tn2, 0, 1)
        STEP(X3, tn3, 1, 0)
        STEP(X4, tn4, 0, 1)
        STEP(X5, tn5, 1, 0)
        STEP(X6, tn6, 0, 1)
        STEP(X7, tn7, 1, 0)
    }
#undef STEP
#undef MF

    if (c < 8) out[d] = hmax;   // 32 unique dims per wave -> out[1][128]
}

// ---------------------------------------------------------------------------
extern "C" void kernel_launch(void* const* d_in, const int* in_sizes, int n_in,
                              void* d_out, int out_size, void* d_ws, size_t ws_size,
                              hipStream_t stream)
{
    const float* embs  = (const float*)d_in[0];
    const int*   pos   = (const int*)  d_in[1];
    const float* W_exp = (const float*)d_in[2];
    const float* b_exp = (const float*)d_in[3];
    const float* W_ih  = (const float*)d_in[4];
    const float* W_hh  = (const float*)d_in[5];
    const float* b_ih  = (const float*)d_in[6];
    const float* b_hh  = (const float*)d_in[7];
    float* out = (float*)d_out;
    float* xg  = (float*)d_ws;   // [SEQ][512] fp32 = 16 MB

    expert_gemv<<<dim3(NEXP * 8), 64, 0, stream>>>(embs, pos, W_exp, b_exp, xg);
    gate_gemm  <<<dim3(256), 256, 0, stream>>>(W_ih, b_ih, b_hh, xg);
    lstm_scan  <<<dim3(1), 256, 0, stream>>>(xg, W_hh, out);
}

// Round 11
// 4277.563 us; speedup vs baseline: 1.1823x; 1.0127x over previous
//
#include <hip/hip_runtime.h>
#include <math.h>

// POSTagEncoder: expert-routed linear -> 1-layer LSTM (i,f,g,o) -> time max-pool.
// S=8192, D=128, E=48. Output [1,128] fp32.
//
// Round-20 scan change (single variable, BIT-EXACT reorder): ASYMMETRIC GATE
// FINISH. LSTM gate-use order is asymmetric: gv is needed first (cst = fv*cst
// + iv*gv), ov last (h = ov*tanh(cst)). R6-form finished g,o together in the
// last MFMA group -> the whole pg->gv->cst->tanh(cst)->po->ov->h chain
// (~90-110cyc + result latency) sat after the final MFMA. New phase-B order:
//   group1: c2x,c3x chunk1 (unchanged; pi/pf selv after, as verified)
//   group2: c2x chunks 2,3  (g COMPLETE; iv/fv sigmoids fill result latency)
//   group3: c3x chunks 2,3  (o completes; pg->gv->ig->cst->tanh(cst) runs
//           UNDER group3's pipe time)
//   tail:   po selv -> ov -> h only (~50cyc vs ~110)
// Dependent MFMA spacing >= 2 (~39cyc). Per-gate chunk accumulation order
// unchanged 0->1->2->3 => BIT-IDENTICAL results.
// Everything else identical to the verified R6/R19 kernel (4331.7us total):
// 4 waves 1/SIMD, slot rotation + pre-barrier own-B read, xg packet in
// chunk-0 stall window, lgkmcnt(1) barrier, branch-free epilogue,
// [t][dim][gate] xg layout, 8 asm xg loads in flight with manual vmcnt(7).

#define SEQ   8192
#define DIM   128
#define NGATE 512
#define NEXP  48

typedef _Float16 v8h  __attribute__((ext_vector_type(8)));
typedef float    v4f  __attribute__((ext_vector_type(4)));

__device__ __forceinline__ float sigm_fast(float x) {
    return __fdividef(1.0f, 1.0f + __expf(-x));   // inf-safe both ends
}
__device__ __forceinline__ float tanh_fast(float x) {
    float e = __expf(2.0f * x);
    return 1.0f - __fdividef(2.0f, e + 1.0f);     // +-1 at saturation
}
__device__ __forceinline__ v8h pack8(float4 a, float4 b) {   // RNE converts
    v8h r;
    r[0]=(_Float16)a.x; r[1]=(_Float16)a.y; r[2]=(_Float16)a.z; r[3]=(_Float16)a.w;
    r[4]=(_Float16)b.x; r[5]=(_Float16)b.y; r[6]=(_Float16)b.z; r[7]=(_Float16)b.w;
    return r;
}
// select component (c&1,c&2) from A (half 0) or B (half 1) per (c&4)
__device__ __forceinline__ float selv(v4f A, v4f B, int c) {
    float a01 = (c & 1) ? A[1] : A[0];
    float a23 = (c & 1) ? A[3] : A[2];
    float av  = (c & 2) ? a23 : a01;
    float b01 = (c & 1) ? B[1] : B[0];
    float b23 = (c & 1) ? B[3] : B[2];
    float bv  = (c & 2) ? b23 : b01;
    return (c & 4) ? bv : av;
}

// ---------------------------------------------------------------------------
// K1a: z[s] = W_exp[pos_ids[s]] @ embs[s] + b_exp  -> xg[s*512 + 0..128)
// ---------------------------------------------------------------------------
__global__ __launch_bounds__(64) void expert_gemv(
    const float* __restrict__ embs, const int* __restrict__ pos_ids,
    const float* __restrict__ W_exp, const float* __restrict__ b_exp,
    float* __restrict__ xg)
{
    __shared__ float Wl[DIM * DIM];          // 64KB, rows XOR-swizzled
    const int e     = blockIdx.x % NEXP;
    const int slice = blockIdx.x / NEXP;     // 0..7
    const int tid   = threadIdx.x;           // 0..63

    const float4* Wg = (const float4*)(W_exp + (size_t)e * DIM * DIM);
    #pragma unroll 4
    for (int it = 0; it < 64; ++it) {
        int idx = it * 64 + tid;             // 0..4095 float4s
        int r = idx >> 5, c4 = idx & 31;
        float4 v = Wg[idx];
        *(float4*)&Wl[r * DIM + (((c4 ^ (r & 31))) << 2)] = v;
    }
    const float b0 = b_exp[e * DIM + tid];
    const float b1 = b_exp[e * DIM + 64 + tid];
    __syncthreads();

    const int r0 = tid, r1 = tid + 64;
    const int sw0 = r0 & 31, sw1 = r1 & 31;
    const int sBeg = slice * 1024, sEnd = sBeg + 1024;
    for (int base = sBeg; base < sEnd; base += 64) {
        int pid = pos_ids[base + tid];
        unsigned long long m = __ballot(pid == e);
        while (m) {
            int t = __builtin_ctzll(m);
            m &= m - 1;
            int s = base + t;
            const float4* ev = (const float4*)(embs + (size_t)s * DIM);
            float a0 = b0, a1 = b1;
            #pragma unroll
            for (int j4 = 0; j4 < 32; ++j4) {
                float4 x  = ev[j4];
                float4 w0 = *(const float4*)&Wl[r0 * DIM + ((j4 ^ sw0) << 2)];
                float4 w1 = *(const float4*)&Wl[r1 * DIM + ((j4 ^ sw1) << 2)];
                a0 = fmaf(w0.x,x.x,fmaf(w0.y,x.y,fmaf(w0.z,x.z,fmaf(w0.w,x.w,a0))));
                a1 = fmaf(w1.x,x.x,fmaf(w1.y,x.y,fmaf(w1.z,x.z,fmaf(w1.w,x.w,a1))));
            }
            float* zp = xg + (size_t)s * NGATE;
            zp[tid]      = a0;
            zp[tid + 64] = a1;
        }
    }
}

// ---------------------------------------------------------------------------
// K1b: gates = W_ih @ z + b_ih + b_hh, stored PERMUTED: xg[s][dim*4 + gate]
// ---------------------------------------------------------------------------
__global__ __launch_bounds__(256) void gate_gemm(
    const float* __restrict__ W_ih, const float* __restrict__ b_ih,
    const float* __restrict__ b_hh, float* __restrict__ xg)
{
    __shared__ float zl[32 * DIM];    // 16KB
    __shared__ float Wl[64 * DIM];    // 32KB
    const int tid = threadIdx.x;
    const int s0  = blockIdx.x * 32;

    #pragma unroll
    for (int it = 0; it < 4; ++it) {
        int idx = it * 256 + tid;
        int tok = idx >> 5, c4 = idx & 31;
        float4 v = *(const float4*)(xg + ((size_t)(s0 + tok)) * NGATE + (c4 << 2));
        *(float4*)&zl[tok * DIM + (((c4 ^ (tok & 31))) << 2)] = v;
    }
    __syncthreads();

    const int lane = tid & 63;
    const int tg   = tid >> 6;
    const int swr  = lane & 31;

    for (int ch = 0; ch < 8; ++ch) {
        #pragma unroll
        for (int it = 0; it < 8; ++it) {
            int idx = it * 256 + tid;
            int r = idx >> 5, c4 = idx & 31;
            float4 v = *(const float4*)(W_ih + ((size_t)(ch * 64 + r)) * DIM + (c4 << 2));
            *(float4*)&Wl[r * DIM + ((c4 ^ (r & 31)) << 2)] = v;
        }
        __syncthreads();

        const int row = ch * 64 + lane;      // 0..511
        const float bias = b_ih[row] + b_hh[row];
        float acc[8];
        #pragma unroll
        for (int k = 0; k < 8; ++k) acc[k] = bias;
        #pragma unroll 8
        for (int j4 = 0; j4 < 32; ++j4) {
            float4 w = *(const float4*)&Wl[lane * DIM + ((j4 ^ swr) << 2)];
            #pragma unroll
            for (int k = 0; k < 8; ++k) {
                int tok = tg * 8 + k;
                float4 z = *(const float4*)&zl[tok * DIM + ((j4 ^ (tok & 31)) << 2)];
                acc[k] = fmaf(w.x,z.x,fmaf(w.y,z.y,fmaf(w.z,z.z,fmaf(w.w,z.w,acc[k]))));
            }
        }
        const int pidx = ((row & 127) << 2) + (row >> 7);   // dim*4 + gate
        #pragma unroll
        for (int k = 0; k < 8; ++k) {
            int tok = tg * 8 + k;
            xg[((size_t)(s0 + tok)) * NGATE + pidx] = acc[k];
        }
        __syncthreads();
    }
}

// ---------------------------------------------------------------------------
// K2: MFMA LSTM scan + max-pool. ONE block, 256 threads (4 waves, 1/SIMD).
// ---------------------------------------------------------------------------
__global__ __launch_bounds__(256, 1) void lstm_scan(
    const float* __restrict__ xg, const float* __restrict__ W_hh,
    float* __restrict__ out)
{
    const int T    = threadIdx.x;
    const int wg   = T >> 6;         // wave id: owns dims [32*wg, 32*wg+32)
    const int lane = T & 63;
    const int q    = lane >> 4;      // quad 0..3
    const int c    = lane & 15;      // A row-in-tile; C column
    const int q8   = q * 8;
    // lanes c>=8 mirror c-8 (duplicate epilogue; write to scratch rows)
    const int d    = wg * 32 + q * 4 + (c & 3) + ((c & 4) ? 16 : 0);
    const int dw   = d + ((c & 8) ? 128 : 0);   // mirror half -> rows 128..255

    __shared__ __align__(16) _Float16 hbuf[2][256];

    // K-chunk slot rotation: slot k <-> chunk (wg+k)&3; slot 0 == own slice.
    const int j0 = wg & 3, j1 = (wg + 1) & 3, j2 = (wg + 2) & 3, j3 = (wg + 3) & 3;
    const int bo0 = j0 * 32 + q8, bo1 = j1 * 32 + q8,
              bo2 = j2 * 32 + q8, bo3 = j3 * 32 + q8;

    // ---- A-fragments: tile (gate G, half H) rows = G*128 + wg*32 + H*16 + c,
    //      4 K-chunks PRE-ROTATED into slots; MFMA-only use -> AGPR-resident --
#define LOADA(G,H) \
    v8h a##G##H##0, a##G##H##1, a##G##H##2, a##G##H##3; { \
        const float4* p = (const float4*)(W_hh + \
            (size_t)((G) * 128 + wg * 32 + (H) * 16 + c) * DIM) + q * 2; \
        a##G##H##0 = pack8(p[8*j0], p[8*j0+1]); \
        a##G##H##1 = pack8(p[8*j1], p[8*j1+1]); \
        a##G##H##2 = pack8(p[8*j2], p[8*j2+1]); \
        a##G##H##3 = pack8(p[8*j3], p[8*j3+1]); }
    LOADA(0,0) LOADA(0,1) LOADA(1,0) LOADA(1,1)
    LOADA(2,0) LOADA(2,1) LOADA(3,0) LOADA(3,1)
#undef LOADA

    float cst  = 0.0f;
    float hmax = -INFINITY;

    if (T < DIM) hbuf[0][T] = (_Float16)0.0f;   // h_0 = 0 (rows 0..127 only)
    __syncthreads();   // drains vmcnt(0): HW counter = 0 at this point; all
                       // compiler-tracked loads (W_hh) are complete.

    // own-slot B for step 0 (zeros; lgkm-tracked by compiler)
    v8h B0cur = *(const v8h*)&hbuf[0][bo0];

    // per-lane xg column pointer ([t][dim][gate] layout)
    const float* xp = xg + 4 * d;

    // 8 asm loads in flight (rows 0..7). Invariant before step t's wait:
    // outstanding = rows t..t+7; vmcnt(7) completes exactly row t.
    v4f X0, X1, X2, X3, X4, X5, X6, X7;
#define PRELD(n) { const float* _p = xp + (size_t)(n) * NGATE; \
    asm volatile("global_load_dwordx4 %0, %1, off" : "=v"(X##n) : "v"(_p)); }
    PRELD(0) PRELD(1) PRELD(2) PRELD(3) PRELD(4) PRELD(5) PRELD(6) PRELD(7)
#undef PRELD

    const v4f Z4 = {0.0f, 0.0f, 0.0f, 0.0f};

#define MF(G,H,K,B,CIN) __builtin_amdgcn_mfma_f32_16x16x32_f16(a##G##H##K, B, CIN, 0, 0, 0)

#define STEP(XV, tn, bf, nbf) { \
    /* foreign MFMA B slices: issue immediately at barrier release */ \
    const v8h B1 = *(const v8h*)&hbuf[bf][bo1]; \
    const v8h B2 = *(const v8h*)&hbuf[bf][bo2]; \
    const v8h B3 = *(const v8h*)&hbuf[bf][bo3]; \
    /* ---- phase A: gates i,f -- 4 chains, chunk-major ---- */ \
    v4f c00 = MF(0,0,0,B0cur,Z4);  v4f c01 = MF(0,1,0,B0cur,Z4); \
    v4f c10 = MF(1,0,0,B0cur,Z4);  v4f c11 = MF(1,1,0,B0cur,Z4); \
    /* xg packet in the first MFMA stall window (B1 latency cover) */ \
    asm volatile("s_waitcnt vmcnt(7)" : "+v"(XV));  /* row-t load complete */ \
    const v4f xcur = XV; \
    { const float* _p = xp + (size_t)(tn) * NGATE; \
      asm volatile("global_load_dwordx4 %0, %1, off" : "=v"(XV) : "v"(_p)); } \
    c00 = MF(0,0,1,B1,c00);  c01 = MF(0,1,1,B1,c01); \
    c10 = MF(1,0,1,B1,c10);  c11 = MF(1,1,1,B1,c11); \
    c00 = MF(0,0,2,B2,c00);  c01 = MF(0,1,2,B2,c01); \
    c10 = MF(1,0,2,B2,c10);  c11 = MF(1,1,2,B2,c11); \
    c00 = MF(0,0,3,B3,c00);  c01 = MF(0,1,3,B3,c01); \
    c10 = MF(1,0,3,B3,c10);  c11 = MF(1,1,3,B3,c11); \
    /* ---- phase B: asymmetric gate finish (g early, o last) ---- */ \
    v4f c20 = MF(2,0,0,B0cur,Z4);  v4f c21 = MF(2,1,0,B0cur,Z4); \
    v4f c30 = MF(3,0,0,B0cur,Z4);  v4f c31 = MF(3,1,0,B0cur,Z4); \
    /* group1: chunk-1 for both g,o (keeps verified pi/pf placement) */ \
    c20 = MF(2,0,1,B1,c20);  c21 = MF(2,1,1,B1,c21); \
    c30 = MF(3,0,1,B1,c30);  c31 = MF(3,1,1,B1,c31); \
    const float pi = selv(c00, c01, c) + xcur[0]; \
    const float pf = selv(c10, c11, c) + xcur[1]; \
    /* group2: g chunks 2,3 -- g COMPLETE */ \
    c20 = MF(2,0,2,B2,c20);  c21 = MF(2,1,2,B2,c21); \
    c20 = MF(2,0,3,B3,c20);  c21 = MF(2,1,3,B3,c21); \
    const float iv = sigm_fast(pi);   /* fills c2x result latency */ \
    const float fv = sigm_fast(pf); \
    /* group3: o chunks 2,3 -- g-side chain runs under this pipe time */ \
    c30 = MF(3,0,2,B2,c30);  c31 = MF(3,1,2,B2,c31); \
    c30 = MF(3,0,3,B3,c30);  c31 = MF(3,1,3,B3,c31); \
    const float pg = selv(c20, c21, c) + xcur[2]; \
    const float gv = tanh_fast(pg); \
    cst = fmaf(fv, cst, iv * gv); \
    const float tc = tanh_fast(cst); \
    /* ---- tail: only o's finish remains after the last MFMA ---- */ \
    const float po = selv(c30, c31, c) + xcur[3]; \
    const float ov = sigm_fast(po); \
    const float h  = ov * tc; \
    hmax = fmaxf(hmax, h); \
    hbuf[nbf][dw] = (_Float16)h; \
    /* own-slot B for NEXT step: same-wave ds ops are pipe-ordered */ \
    B0cur = *(const v8h*)&hbuf[nbf][bo0]; \
    /* lgkmcnt(1): h ds_write drained (cross-wave visible at barrier); */ \
    /* B0cur's ds_read latency overlaps the barrier wait.              */ \
    asm volatile("s_waitcnt lgkmcnt(1)\n\ts_barrier" ::: "memory"); }

    for (int t = 0; t < SEQ; t += 8) {
        const int tn0 = (t +  8 < SEQ) ? t +  8 : SEQ - 1;
        const int tn1 = (t +  9 < SEQ) ? t +  9 : SEQ - 1;
        const int tn2 = (t + 10 < SEQ) ? t + 10 : SEQ - 1;
        const int tn3 = (t + 11 < SEQ) ? t + 11 : SEQ - 1;
        const int tn4 = (t + 12 < SEQ) ? t + 12 : SEQ - 1;
        const int tn5 = (t + 13 < SEQ) ? t + 13 : SEQ - 1;
        const int tn6 = (t + 14 < SEQ) ? t + 14 : SEQ - 1;
        const int tn7 = (t + 15 < SEQ) ? t + 15 : SEQ - 1;
        STEP(X0, tn0, 0, 1)
        STEP(X1, tn1, 1, 0)
        STEP(X2, tn2, 0, 1)
        STEP(X3, tn3, 1, 0)
        STEP(X4, tn4, 0, 1)
        STEP(X5, tn5, 1, 0)
        STEP(X6, tn6, 0, 1)
        STEP(X7, tn7, 1, 0)
    }
#undef STEP
#undef MF

    if (c < 8) out[d] = hmax;   // 32 unique dims per wave -> out[1][128]
}

// ---------------------------------------------------------------------------
extern "C" void kernel_launch(void* const* d_in, const int* in_sizes, int n_in,
                              void* d_out, int out_size, void* d_ws, size_t ws_size,
                              hipStream_t stream)
{
    const float* embs  = (const float*)d_in[0];
    const int*   pos   = (const int*)  d_in[1];
    const float* W_exp = (const float*)d_in[2];
    const float* b_exp = (const float*)d_in[3];
    const float* W_ih  = (const float*)d_in[4];
    const float* W_hh  = (const float*)d_in[5];
    const float* b_ih  = (const float*)d_in[6];
    const float* b_hh  = (const float*)d_in[7];
    float* out = (float*)d_out;
    float* xg  = (float*)d_ws;   // [SEQ][512] fp32 = 16 MB

    expert_gemv<<<dim3(NEXP * 8), 64, 0, stream>>>(embs, pos, W_exp, b_exp, xg);
    gate_gemm  <<<dim3(256), 256, 0, stream>>>(W_ih, b_ih, b_hh, xg);
    lstm_scan  <<<dim3(1), 256, 0, stream>>>(xg, W_hh, out);
}